// Round 1
// baseline (1146.489 us; speedup 1.0000x reference)
//
#include <hip/hip_runtime.h>

#define DEV static __device__ __forceinline__

DEV float bf2f(unsigned short u){ union{unsigned i; float f;} a; a.i=((unsigned)u)<<16; return a.f; }
DEV unsigned short f2bf(float f){ union{unsigned i; float f;} a; a.f=f; unsigned r=a.i+0x7fffu+((a.i>>16)&1u); return (unsigned short)(r>>16); }

// ---------------- CSR build ----------------
__global__ __launch_bounds__(256) void hist_kernel(const int* __restrict__ dst, int* __restrict__ deg, int E){
  int i=blockIdx.x*256+threadIdx.x, st=gridDim.x*256;
  for(;i<E;i+=st) atomicAdd(&deg[dst[i]],1);
}

__global__ __launch_bounds__(1024) void scan_kernel(const int* __restrict__ deg, int* __restrict__ offs,
    int* __restrict__ cursor, float* __restrict__ dinv, int M){
  __shared__ int sums[1024];
  int t=threadIdx.x;
  int per=(M+1023)>>10;
  int s0=t*per, s1=min(s0+per,M);
  int s=0;
  for(int i=s0;i<s1;i++) s+=deg[i];
  sums[t]=s; __syncthreads();
  for(int o=1;o<1024;o<<=1){
    int v=(t>=o)?sums[t-o]:0;
    __syncthreads();
    if(t>=o) sums[t]+=v;
    __syncthreads();
  }
  int run=(t>0)?sums[t-1]:0;
  for(int i=s0;i<s1;i++){
    int d=deg[i];
    offs[i]=run; cursor[i]=run;
    dinv[i]=rsqrtf((float)(d+1));
    run+=d;
  }
}

__global__ __launch_bounds__(256) void fill_kernel(const int* __restrict__ src, const int* __restrict__ dst,
    int* __restrict__ cursor, int* __restrict__ col, int E){
  int i=blockIdx.x*256+threadIdx.x, st=gridDim.x*256;
  for(;i<E;i+=st){ int d=dst[i]; int p=atomicAdd(&cursor[d],1); col[p]=src[i]; }
}

// ---------------- xs0 = dinv * x, padded to 22 cols ----------------
__global__ __launch_bounds__(256) void scale_kernel(const float* __restrict__ x, const float* __restrict__ dinv,
    float* __restrict__ xs, int M){
  int idx=blockIdx.x*256+threadIdx.x;
  if(idx>=M*11) return;
  int n=idx/11, l=idx-n*11;
  float dv=dinv[n];
  float a=x[(size_t)n*21+2*l];
  float b=(2*l+1<21)?x[(size_t)n*21+2*l+1]:0.f;
  ((float2*)xs)[(size_t)n*11+l]=make_float2(dv*a,dv*b);
}

// ---------------- aggregation: out[d] = dinv[d]*(in[d] + sum_{e:dst=d} in[src_e]) ----------------
// in is pre-scaled by dinv[src]. Each GROUP of lanes handles one node; lane -> float2 (2 dims).
template<int GROUP,int F2,bool BR>
__global__ __launch_bounds__(256) void agg_kernel(const float* __restrict__ xs, const int* __restrict__ col,
    const int* __restrict__ offs, const int* __restrict__ deg, const float* __restrict__ dinv,
    const float* __restrict__ bias, float* __restrict__ out, int M){
  int gid=blockIdx.x*256+threadIdx.x;
  int node=gid/GROUP, lane=gid%GROUP;
  if(node>=M) return;
  bool act=lane<F2;
  const float2* base=(const float2*)xs;
  float ax=0.f, ay=0.f;
  if(act){ float2 v=base[(size_t)node*F2+lane]; ax=v.x; ay=v.y; }
  int e0=offs[node], d=deg[node];
  int i=0;
  for(;i+4<=d;i+=4){
    int s0=col[e0+i], s1=col[e0+i+1], s2=col[e0+i+2], s3=col[e0+i+3];
    if(act){
      float2 v0=base[(size_t)s0*F2+lane];
      float2 v1=base[(size_t)s1*F2+lane];
      float2 v2=base[(size_t)s2*F2+lane];
      float2 v3=base[(size_t)s3*F2+lane];
      ax+=(v0.x+v1.x)+(v2.x+v3.x);
      ay+=(v0.y+v1.y)+(v2.y+v3.y);
    }
  }
  for(;i<d;i++){
    int s=col[e0+i];
    if(act){ float2 v=base[(size_t)s*F2+lane]; ax+=v.x; ay+=v.y; }
  }
  if(!act) return;
  float dv=dinv[node];
  ax*=dv; ay*=dv;
  if constexpr(BR){
    ax=fmaxf(ax+bias[2*lane],0.f);
    ay=fmaxf(ay+bias[2*lane+1],0.f);
  }
  ((float2*)out)[(size_t)node*F2+lane]=make_float2(ax,ay);
}

// ---------------- tiled GEMM: Out[M,N] = epilogue(X[M,K] @ W[RK,N]) ----------------
template<int K,int RK,int N,int NB,bool INBF,bool OUTBF,bool BR,bool DV>
__global__ __launch_bounds__(256) void gemm_kernel(const void* __restrict__ Xin, const float* __restrict__ W,
    const float* __restrict__ bias, const float* __restrict__ dinv, void* __restrict__ Out, int M){
  __shared__ float Wl[K*N];
  __shared__ float Xl[NB*K];
  int tid=threadIdx.x;
  for(int i=tid;i<K*N;i+=256){ int r=i/N; Wl[i]=(r<RK)?W[i]:0.f; }
  int nbase=blockIdx.x*NB;
  if constexpr(!INBF){
    const float* X=(const float*)Xin;
    for(int i=tid;i<NB*K;i+=256){ int r=i/K, c=i-r*K; int n=nbase+r; Xl[i]=(n<M)?X[(size_t)n*K+c]:0.f; }
  } else {
    const unsigned short* X=(const unsigned short*)Xin;
    for(int i=tid;i<NB*K;i+=256){ int r=i/K, c=i-r*K; int n=nbase+r; Xl[i]=(n<M)?bf2f(X[(size_t)n*K+c]):0.f; }
  }
  __syncthreads();
  constexpr int ROWS=NB/4;
  constexpr int NC=N/64;
  int lane=tid&63, wave=tid>>6;
  int rowbase=wave*ROWS;
  float acc[ROWS][NC];
  #pragma unroll
  for(int i=0;i<ROWS;i++)
    #pragma unroll
    for(int j=0;j<NC;j++) acc[i][j]=0.f;

  if constexpr((K&3)==0){
    for(int k=0;k<K;k+=4){
      float wv[4][NC];
      #pragma unroll
      for(int q=0;q<4;q++)
        #pragma unroll
        for(int j=0;j<NC;j++) wv[q][j]=Wl[(k+q)*N+j*64+lane];
      #pragma unroll
      for(int i=0;i<ROWS;i++){
        float4 xv=*(const float4*)&Xl[(rowbase+i)*K+k];
        #pragma unroll
        for(int j=0;j<NC;j++){
          acc[i][j]=fmaf(xv.x,wv[0][j],acc[i][j]);
          acc[i][j]=fmaf(xv.y,wv[1][j],acc[i][j]);
          acc[i][j]=fmaf(xv.z,wv[2][j],acc[i][j]);
          acc[i][j]=fmaf(xv.w,wv[3][j],acc[i][j]);
        }
      }
    }
  } else {
    for(int k=0;k<K;k++){
      float wv[NC];
      #pragma unroll
      for(int j=0;j<NC;j++) wv[j]=Wl[k*N+j*64+lane];
      #pragma unroll
      for(int i=0;i<ROWS;i++){
        float xv=Xl[(rowbase+i)*K+k];
        #pragma unroll
        for(int j=0;j<NC;j++) acc[i][j]=fmaf(xv,wv[j],acc[i][j]);
      }
    }
  }
  float bv[NC];
  if constexpr(BR){
    #pragma unroll
    for(int j=0;j<NC;j++) bv[j]=bias[j*64+lane];
  }
  #pragma unroll
  for(int i=0;i<ROWS;i++){
    int n=nbase+rowbase+i;
    if(n<M){
      float dv=1.f;
      if constexpr(DV) dv=dinv[n];
      #pragma unroll
      for(int j=0;j<NC;j++){
        float v=acc[i][j];
        if constexpr(BR) v=fmaxf(v+bv[j],0.f);
        if constexpr(DV) v*=dv;
        int c=j*64+lane;
        if constexpr(OUTBF) ((unsigned short*)Out)[(size_t)n*N+c]=f2bf(v);
        else ((float*)Out)[(size_t)n*N+c]=v;
      }
    }
  }
}

// ---------------- fused MLP head: out = (relu(h@Wl1+bl1))@Wl2 + bl2 ----------------
__global__ __launch_bounds__(256) void mlp_kernel(const float* __restrict__ h, const float* __restrict__ W1,
    const float* __restrict__ b1, const float* __restrict__ W2, const float* __restrict__ b2,
    float* __restrict__ out, int M){
  __shared__ float W1s[64*20];
  __shared__ float b1s[20];
  __shared__ float W2s[20];
  __shared__ float b2s;
  int tid=threadIdx.x;
  for(int i=tid;i<1280;i+=256) W1s[i]=W1[i];
  if(tid<20){ b1s[tid]=b1[tid]; W2s[tid]=W2[tid]; }
  if(tid==0) b2s=b2[0];
  __syncthreads();
  int n=blockIdx.x*256+tid;
  if(n>=M) return;
  float acc[20];
  #pragma unroll
  for(int j=0;j<20;j++) acc[j]=b1s[j];
  const float4* hp=(const float4*)(h+(size_t)n*64);
  for(int k4=0;k4<16;k4++){
    float4 hv=hp[k4];
    #pragma unroll
    for(int j=0;j<20;j++){
      acc[j]=fmaf(hv.x,W1s[(k4*4+0)*20+j],acc[j]);
      acc[j]=fmaf(hv.y,W1s[(k4*4+1)*20+j],acc[j]);
      acc[j]=fmaf(hv.z,W1s[(k4*4+2)*20+j],acc[j]);
      acc[j]=fmaf(hv.w,W1s[(k4*4+3)*20+j],acc[j]);
    }
  }
  float r=b2s;
  #pragma unroll
  for(int j=0;j<20;j++) r+=fmaxf(acc[j],0.f)*W2s[j];
  out[n]=r;
}

extern "C" void kernel_launch(void* const* d_in, const int* in_sizes, int n_in,
                              void* d_out, int out_size, void* d_ws, size_t ws_size,
                              hipStream_t stream){
  const float* x  =(const float*)d_in[0];
  const int*   ei =(const int*)  d_in[1];
  const float* W1 =(const float*)d_in[2];
  const float* b1 =(const float*)d_in[3];
  const float* W2 =(const float*)d_in[4];
  const float* b2 =(const float*)d_in[5];
  const float* W3 =(const float*)d_in[6];
  const float* b3 =(const float*)d_in[7];
  const float* Wl1=(const float*)d_in[8];
  const float* bl1=(const float*)d_in[9];
  const float* Wl2=(const float*)d_in[10];
  const float* bl2=(const float*)d_in[11];
  const int M=in_sizes[0]/21;
  const int E=in_sizes[1]/2;
  const int* srcp=ei;
  const int* dstp=ei+(size_t)E;

  char* ws=(char*)d_ws;
  size_t off=0;
  auto alloc=[&](size_t bytes)->void*{
    off=(off+255)&~(size_t)255;
    void* p=ws+off; off+=bytes; return p;
  };
  int*   deg   =(int*)  alloc((size_t)M*4);
  int*   offs  =(int*)  alloc((size_t)M*4);
  int*   cursor=(int*)  alloc((size_t)M*4);
  float* dinv  =(float*)alloc((size_t)M*4);
  int*   col   =(int*)  alloc((size_t)E*4);
  // four reusable 256B-per-node slots
  float* A=(float*)alloc((size_t)M*256);   // xs0 f32[M,22]  -> h2 bf16[M,128]
  float* B=(float*)alloc((size_t)M*256);   // Y1  f32[M,22]  -> ts  f32[M,64]
  float* C=(float*)alloc((size_t)M*256);   // xs1 f32[M,64]  -> h3  f32[M,64]
  float* D=(float*)alloc((size_t)M*256);   // Y2  f32[M,64]
  (void)ws_size;(void)n_in;(void)out_size;

  hipMemsetAsync(deg,0,(size_t)M*4,stream);
  hist_kernel<<<2048,256,0,stream>>>(dstp,deg,E);
  scan_kernel<<<1,1024,0,stream>>>(deg,offs,cursor,dinv,M);
  fill_kernel<<<2048,256,0,stream>>>(srcp,dstp,cursor,col,E);

  // layer 1: aggregate in 21-dim, then GEMM 21->64 (bias+relu+dinv into xs1)
  scale_kernel<<<(M*11+255)/256,256,0,stream>>>(x,dinv,A,M);
  agg_kernel<16,11,false><<<(M*16+255)/256,256,0,stream>>>(A,col,offs,deg,dinv,nullptr,B,M);
  gemm_kernel<22,21,64,64,false,false,true,true><<<(M+63)/64,256,0,stream>>>(B,W1,b1,dinv,C,M);
  // layer 2: aggregate in 64-dim (pre-GEMM), then GEMM 64->128 (bias+relu), h2 in bf16
  agg_kernel<32,32,false><<<(M*32+255)/256,256,0,stream>>>(C,col,offs,deg,dinv,nullptr,D,M);
  gemm_kernel<64,64,128,64,false,true,true,false><<<(M+63)/64,256,0,stream>>>(D,W2,b2,nullptr,A,M);
  // layer 3: GEMM 128->64 first (dinv into ts), then aggregate (bias+relu epilogue)
  gemm_kernel<128,128,64,32,true,false,false,true><<<(M+31)/32,256,0,stream>>>(A,W3,nullptr,dinv,B,M);
  agg_kernel<32,32,true><<<(M*32+255)/256,256,0,stream>>>(B,col,offs,deg,dinv,b3,C,M);
  // MLP head
  mlp_kernel<<<(M+255)/256,256,0,stream>>>(C,Wl1,bl1,Wl2,bl2,(float*)d_out,M);
}